// Round 5
// baseline (119.926 us; speedup 1.0000x reference)
//
#include <hip/hip_runtime.h>
#include <hip/hip_bf16.h>
#include <math.h>

#define S_LEN 2048
#define E_DIM 1024
#define NHEAD 8
#define DHEAD 128
#define MEPS 1e-6f
#define LNEPS 1e-5f

typedef __bf16 bf16x8 __attribute__((ext_vector_type(8)));
typedef float f32x4 __attribute__((ext_vector_type(4)));

__device__ inline void split8(const float* x, bf16x8& hi, bf16x8& lo) {
#pragma unroll
  for (int e = 0; e < 8; ++e) {
    float v = x[e];
    __bf16 h = (__bf16)v;
    hi[e] = h;
    lo[e] = (__bf16)(v - (float)h);
  }
}

// ---------- kernel 1: gates. wave-per-output-column, register-cached weights ----------
__global__ __launch_bounds__(1024) void gates_kernel(
    const float* __restrict__ q, const float* __restrict__ k, const float* __restrict__ v,
    const float* __restrict__ igw, const float* __restrict__ igb,
    const float* __restrict__ fgw, const float* __restrict__ fgb,
    float* __restrict__ ig, double* __restrict__ ls) {
  int t = threadIdx.x, wave = t >> 6, lane = t & 63;
  int c = wave;  // 0..15
  const float* wrow = (c < 8) ? (igw + c * 3072) : (fgw + (c - 8) * 3072);
  float4 wreg[12];
#pragma unroll
  for (int j = 0; j < 12; ++j) wreg[j] = *(const float4*)(wrow + j * 256 + lane * 4);
  int r0 = blockIdx.x * 8;
  for (int r = 0; r < 8; ++r) {
    int row = r0 + r;
    float acc = 0.f;
#pragma unroll
    for (int j = 0; j < 12; ++j) {
      const float* xs = (j < 4) ? (q + (size_t)row * 1024 + j * 256)
                      : (j < 8) ? (k + (size_t)row * 1024 + (j - 4) * 256)
                                : (v + (size_t)row * 1024 + (j - 8) * 256);
      float4 xv = *(const float4*)(xs + lane * 4);
      acc = fmaf(xv.x, wreg[j].x, acc);
      acc = fmaf(xv.y, wreg[j].y, acc);
      acc = fmaf(xv.z, wreg[j].z, acc);
      acc = fmaf(xv.w, wreg[j].w, acc);
    }
#pragma unroll
    for (int off = 1; off < 64; off <<= 1) acc += __shfl_xor(acc, off);
    if (lane == 0) {
      if (c < 8) {
        ig[c * S_LEN + row] = acc + igb[c];
      } else {
        double x = (double)(acc + fgb[c - 8]);
        ls[(c - 8) * S_LEN + row] = fmin(x, 0.0) - log1p(exp(-fabs(x)));
      }
    }
  }
}

// ---------- kernel 2: per-head f64 scan ----------
__global__ void scan_kernel(const float* __restrict__ ig, const double* __restrict__ ls,
                            double* __restrict__ g, double* __restrict__ Mv,
                            float* __restrict__ rexpv) {
  int h = blockIdx.x;
  int lane = threadIdx.x;  // 64
  double cs0[32];
  const double* lsp = ls + h * S_LEN + lane * 32;
  double run = 0.0;
#pragma unroll
  for (int e = 0; e < 32; ++e) { run += lsp[e]; cs0[e] = run; }
  double incl = run;
#pragma unroll
  for (int off = 1; off < 64; off <<= 1) {
    double nb = __shfl_up(incl, off);
    if (lane >= off) incl += nb;
  }
  double base = __shfl_up(incl, 1);
  if (lane == 0) base = 0.0;
#pragma unroll
  for (int e = 0; e < 32; ++e) cs0[e] += base;

  const float* igp = ig + h * S_LEN + lane * 32;
  double gv[32];
#pragma unroll
  for (int e = 0; e < 32; ++e) {
    gv[e] = (double)igp[e] - cs0[e];
    g[h * S_LEN + lane * 32 + e] = gv[e];
  }
  double pm = -INFINITY;
#pragma unroll
  for (int e = 0; e < 32; ++e) { pm = fmax(pm, gv[e]); gv[e] = pm; }
  double inclm = pm;
#pragma unroll
  for (int off = 1; off < 64; off <<= 1) {
    double nb = __shfl_up(inclm, off);
    if (lane >= off) inclm = fmax(inclm, nb);
  }
  double basem = __shfl_up(inclm, 1);
  if (lane == 0) basem = -INFINITY;
#pragma unroll
  for (int e = 0; e < 32; ++e) {
    double Mi = fmax(basem, gv[e]);
    Mv[h * S_LEN + lane * 32 + e] = Mi;
    rexpv[h * S_LEN + lane * 32 + e] = __expf(-(float)(cs0[e] + Mi));
  }
}

// ---------- kernel 2c: rebase g/M to f32 per (head, 128-row q-group) ----------
// gq[(h*16+qg)*2048 + j] = f32(g[h][j] - M[h][qg*128]);  Mq[h*2048+i] = f32(M[h][i] - M[h][(i>>7)*128])
__global__ __launch_bounds__(256) void rebase_kernel(
    const double* __restrict__ g, const double* __restrict__ Mv,
    float* __restrict__ gq, float* __restrict__ Mq) {
  int b = blockIdx.x;         // 128 = 8 heads x 16 groups
  int h = b >> 4, qg = b & 15;
  int tid = threadIdx.x;
  double base = Mv[h * S_LEN + qg * 128];
#pragma unroll
  for (int it = 0; it < 8; ++it) {
    int j = it * 256 + tid;
    gq[(size_t)(h * 16 + qg) * S_LEN + j] = (float)(g[h * S_LEN + j] - base);
  }
  if (tid < 128) {
    int i = qg * 128 + tid;
    Mq[h * S_LEN + i] = (float)(Mv[h * S_LEN + i] - base);
  }
}

// ---------- kernel 3: pre-convert K,V to fragment-major bf16 (K hi+lo, V hi) ----------
__global__ __launch_bounds__(256) void convert_kernel(
    const float* __restrict__ k, const float* __restrict__ v,
    __bf16* __restrict__ KfH, __bf16* __restrict__ KfL, __bf16* __restrict__ VfH) {
  int h = blockIdx.x >> 5, kvt = blockIdx.x & 31;
  int t = threadIdx.x;
  __shared__ float Kl[64][132], Vl[64][132];
  int kvbase = kvt * 64;
#pragma unroll
  for (int it = 0; it < 8; ++it) {
    int fid = it * 256 + t;
    int r = fid >> 5, c4 = (fid & 31) * 4;
    *(float4*)&Kl[r][c4] = *(const float4*)(k + (size_t)(kvbase + r) * E_DIM + h * DHEAD + c4);
    *(float4*)&Vl[r][c4] = *(const float4*)(v + (size_t)(kvbase + r) * E_DIM + h * DHEAD + c4);
  }
  __syncthreads();
  size_t tb = (size_t)(h * 32 + kvt) * 8192;
#pragma unroll
  for (int it = 0; it < 4; ++it) {
    int s = it * 256 + t;
    int f = s >> 6, l = s & 63;
    int l15 = l & 15, lh = l >> 4;
    {
      int krow = (f >> 2) * 16 + l15, d0 = (f & 3) * 32 + lh * 8;
      float buf[8];
#pragma unroll
      for (int e = 0; e < 8; ++e) buf[e] = Kl[krow][d0 + e];
      bf16x8 fh, fl; split8(buf, fh, fl);
      *(bf16x8*)(KfH + tb + (size_t)s * 8) = fh;
      *(bf16x8*)(KfL + tb + (size_t)s * 8) = fl;
    }
    {
      int j0 = (f >> 3) * 32 + lh * 8, d = (f & 7) * 16 + l15;
      bf16x8 fh;
#pragma unroll
      for (int e = 0; e < 8; ++e) fh[e] = (__bf16)Vl[j0 + e][d];
      *(bf16x8*)(VfH + tb + (size_t)s * 8) = fh;
    }
  }
}

// ---------- kernel 4: attention. block = (h, qg128, kv-split of nsplit), 8 waves ----------
__global__ __launch_bounds__(512, 4) void attn_kernel(
    const float* __restrict__ q,
    const __bf16* __restrict__ KfH, const __bf16* __restrict__ KfL,
    const __bf16* __restrict__ VfH,
    const float* __restrict__ gq, const float* __restrict__ Mq,
    float* __restrict__ part, float* __restrict__ bpart, int nsplit) {
  int idx = blockIdx.x;
  int h = idx & 7;                   // XCD-pinned per head
  int j2 = idx >> 3;
  int split = j2 % nsplit;
  int qg = 15 - (j2 / nsplit);       // heavy-first
  int T = 2 * qg + 2;
  int kb_lo = (split * T) / nsplit;
  int kb_hi = ((split + 1) * T) / nsplit;
  int tid = threadIdx.x, wave = tid >> 6, lane = tid & 63;
  int lhalf = lane >> 4, l15 = lane & 15;
  int wr0 = qg * 128 + wave * 16;
  const float scale = 0.08838834764831845f;  // 1/sqrt(128)

  __shared__ float4 smem4[64 * 1024 / 16];   // [KH 16K][KL 16K][VH 16K][P 8x2K]
  char* smem = (char*)smem4;
  char* PwH = smem + 48 * 1024 + wave * 2048;

  // Q fragments hi/lo
  bf16x8 qfh[4], qfl[4];
  {
    const float* qp = q + (size_t)(wr0 + l15) * E_DIM + h * DHEAD + lhalf * 8;
#pragma unroll
    for (int kc = 0; kc < 4; ++kc) {
      float buf[8];
      *(float4*)&buf[0] = *(const float4*)(qp + kc * 32);
      *(float4*)&buf[4] = *(const float4*)(qp + kc * 32 + 4);
      split8(buf, qfh[kc], qfl[kc]);
    }
  }
  float Mreg[4];
#pragma unroll
  for (int rg = 0; rg < 4; ++rg) Mreg[rg] = Mq[h * S_LEN + wr0 + lhalf * 4 + rg];
  const float* gqh = gq + (size_t)(h * 16 + qg) * S_LEN;

  f32x4 acc[8];
#pragma unroll
  for (int nt = 0; nt < 8; ++nt) acc[nt] = (f32x4){0.f, 0.f, 0.f, 0.f};
  float bacc[4] = {0.f, 0.f, 0.f, 0.f};

  bf16x8 sreg[6];
  auto STAGE = [&](int kb) {
    size_t tb = (size_t)(h * 32 + kb) * 8192;
#pragma unroll
    for (int jj = 0; jj < 2; ++jj) {
      sreg[jj]     = *(const bf16x8*)(KfH + tb + (size_t)(jj * 512 + tid) * 8);
      sreg[2 + jj] = *(const bf16x8*)(KfL + tb + (size_t)(jj * 512 + tid) * 8);
      sreg[4 + jj] = *(const bf16x8*)(VfH + tb + (size_t)(jj * 512 + tid) * 8);
    }
  };
  if (kb_lo < kb_hi) STAGE(kb_lo);

  for (int kb = kb_lo; kb < kb_hi; ++kb) {
    int kvbase = kb * 64;
    // regs -> LDS (compiler inserts vmcnt waits per reg)
#pragma unroll
    for (int jj = 0; jj < 2; ++jj) {
      *(bf16x8*)(smem +          (jj * 512 + tid) * 16) = sreg[jj];
      *(bf16x8*)(smem + 16384 +  (jj * 512 + tid) * 16) = sreg[2 + jj];
      *(bf16x8*)(smem + 32768 +  (jj * 512 + tid) * 16) = sreg[4 + jj];
    }
    if (kb + 1 < kb_hi) STAGE(kb + 1);   // next tile flies during compute
    asm volatile("s_waitcnt lgkmcnt(0)" ::: "memory");
    __builtin_amdgcn_s_barrier();

    float gj4[4];
#pragma unroll
    for (int ct = 0; ct < 4; ++ct) gj4[ct] = gqh[kvbase + ct * 16 + l15];

    // ---- QK^T: 4 independent accumulator chains, split product ----
    f32x4 cacc[4];
#pragma unroll
    for (int ct = 0; ct < 4; ++ct) cacc[ct] = (f32x4){0.f, 0.f, 0.f, 0.f};
    __builtin_amdgcn_s_setprio(1);
#pragma unroll
    for (int kc = 0; kc < 4; ++kc) {
#pragma unroll
      for (int ct = 0; ct < 4; ++ct) {
        int f = ct * 4 + kc;
        bf16x8 kh = *(const bf16x8*)(smem + f * 1024 + lane * 16);
        bf16x8 kl = *(const bf16x8*)(smem + 16384 + f * 1024 + lane * 16);
        cacc[ct] = __builtin_amdgcn_mfma_f32_16x16x32_bf16(qfh[kc], kh, cacc[ct], 0, 0, 0);
        cacc[ct] = __builtin_amdgcn_mfma_f32_16x16x32_bf16(qfh[kc], kl, cacc[ct], 0, 0, 0);
        cacc[ct] = __builtin_amdgcn_mfma_f32_16x16x32_bf16(qfl[kc], kh, cacc[ct], 0, 0, 0);
      }
    }
    __builtin_amdgcn_s_setprio(0);

    // ---- weights + P store (hi only, per-wave LDS, swizzled) ----
#pragma unroll
    for (int ct = 0; ct < 4; ++ct) {
      int j = kvbase + ct * 16 + l15;
#pragma unroll
      for (int rg = 0; rg < 4; ++rg) {
        int i = wr0 + lhalf * 4 + rg;
        float pv = 0.f;
        if (j <= i) pv = cacc[ct][rg] * scale * __expf(gj4[ct] - Mreg[rg]);
        bacc[rg] += pv;
        int poff = ((lhalf * 4 + rg) * 128 + (ct * 16 + l15) * 2) ^ (((lhalf * 4 + rg) & 7) << 4);
        *(__bf16*)(PwH + poff) = (__bf16)pv;
      }
    }

    // ---- PV: 8 independent chains (P hi x V hi) ----
    __builtin_amdgcn_s_setprio(1);
#pragma unroll
    for (int kc2 = 0; kc2 < 2; ++kc2) {
      int poff = (l15 * 128 + (kc2 * 32 + lhalf * 8) * 2) ^ ((l15 & 7) << 4);
      bf16x8 pfh = *(const bf16x8*)(PwH + poff);
#pragma unroll
      for (int nt = 0; nt < 8; ++nt) {
        int f2 = kc2 * 8 + nt;
        bf16x8 vfh = *(const bf16x8*)(smem + 32768 + f2 * 1024 + lane * 16);
        acc[nt] = __builtin_amdgcn_mfma_f32_16x16x32_bf16(pfh, vfh, acc[nt], 0, 0, 0);
      }
    }
    __builtin_amdgcn_s_setprio(0);
    __builtin_amdgcn_s_barrier();   // all waves done reading before restage
  }

  // ---- partial write ----
  float bred[4];
#pragma unroll
  for (int rg = 0; rg < 4; ++rg) {
    float b = bacc[rg];
    b += __shfl_xor(b, 1); b += __shfl_xor(b, 2);
    b += __shfl_xor(b, 4); b += __shfl_xor(b, 8);
    bred[rg] = b;
  }
  int task = (h * 16 + qg) * nsplit + split;
  if (l15 == 0) {
#pragma unroll
    for (int rg = 0; rg < 4; ++rg)
      bpart[task * 128 + wave * 16 + lhalf * 4 + rg] = bred[rg];
  }
  size_t pb = ((size_t)task * 128 + wave * 16) * 128;
#pragma unroll
  for (int nt = 0; nt < 8; ++nt)
#pragma unroll
    for (int rg = 0; rg < 4; ++rg)
      part[pb + (size_t)(lhalf * 4 + rg) * 128 + nt * 16 + l15] = acc[nt][rg];
}

// ---------- kernel 5: combine partials + normalize + LayerNorm (fused) ----------
__global__ __launch_bounds__(256) void combine_ln_kernel(
    const float* __restrict__ part, const float* __restrict__ bpart,
    const float* __restrict__ rexpv, const float* __restrict__ lnw,
    float* __restrict__ out, int nsplit) {
  int t = blockIdx.x;          // token
  int tid = threadIdx.x;
  int qg = t >> 7, rloc = t & 127;
  int e = tid * 4;
  int h = e >> 7, d = e & 127;
  int task0 = (h * 16 + qg) * nsplit;
  float4 a = {0.f, 0.f, 0.f, 0.f};
  float b = 0.f;
  for (int s = 0; s < nsplit; ++s) {
    size_t p = ((size_t)(task0 + s) * 128 + rloc) * 128 + d;
    float4 x = *(const float4*)(part + p);
    a.x += x.x; a.y += x.y; a.z += x.z; a.w += x.w;
    b += bpart[(task0 + s) * 128 + rloc];
  }
  float norm = fmaxf(fabsf(b), rexpv[h * S_LEN + t]) + MEPS;
  float inv = 1.f / norm;
  float4 hv;
  hv.x = a.x * inv; hv.y = a.y * inv; hv.z = a.z * inv; hv.w = a.w * inv;

  float sum = hv.x + hv.y + hv.z + hv.w;
  float sq  = hv.x * hv.x + hv.y * hv.y + hv.z * hv.z + hv.w * hv.w;
#pragma unroll
  for (int off = 1; off < 64; off <<= 1) {
    sum += __shfl_xor(sum, off);
    sq  += __shfl_xor(sq, off);
  }
  __shared__ float ps[4][2];
  int wave = tid >> 6;
  if ((tid & 63) == 0) { ps[wave][0] = sum; ps[wave][1] = sq; }
  __syncthreads();
  float ts = ps[0][0] + ps[1][0] + ps[2][0] + ps[3][0];
  float tq = ps[0][1] + ps[1][1] + ps[2][1] + ps[3][1];
  float mu = ts * (1.f / E_DIM);
  float var = tq * (1.f / E_DIM) - mu * mu;
  float rstd = rsqrtf(var + LNEPS);
  float4 w = *(const float4*)(lnw + e);
  float4 o;
  o.x = (hv.x - mu) * rstd * w.x;
  o.y = (hv.y - mu) * rstd * w.y;
  o.z = (hv.z - mu) * rstd * w.z;
  o.w = (hv.w - mu) * rstd * w.w;
  *(float4*)(out + (size_t)t * E_DIM + e) = o;
}

extern "C" void kernel_launch(void* const* d_in, const int* in_sizes, int n_in,
                              void* d_out, int out_size, void* d_ws, size_t ws_size,
                              hipStream_t stream) {
  const float* q   = (const float*)d_in[0];
  const float* k   = (const float*)d_in[1];
  const float* v   = (const float*)d_in[2];
  const float* igw = (const float*)d_in[3];
  const float* igb = (const float*)d_in[4];
  const float* fgw = (const float*)d_in[5];
  const float* fgb = (const float*)d_in[6];
  const float* lnw = (const float*)d_in[7];
  float* out = (float*)d_out;

  char* base = (char*)d_ws;
  float*  ig    = (float*)(base + 0);             // 64KB
  double* ls    = (double*)(base + 64 * 1024);    // 128KB
  double* g64   = (double*)(base + 192 * 1024);   // 128KB
  double* M64   = (double*)(base + 320 * 1024);   // 128KB
  float*  rexpv = (float*)(base + 448 * 1024);    // 64KB
  float*  gq    = (float*)(base + 512 * 1024);    // 1MB  [8][16][2048]
  float*  Mq    = (float*)(base + 1536 * 1024);   // 64KB
  float*  bpart = (float*)(base + 1600 * 1024);   // 256KB max
  __bf16* KfH   = (__bf16*)(base + 2 * 1024 * 1024);    // 4MB
  __bf16* KfL   = (__bf16*)(base + 6 * 1024 * 1024);    // 4MB
  __bf16* VfH   = (__bf16*)(base + 10 * 1024 * 1024);   // 4MB
  float*  part  = (float*)(base + 14 * 1024 * 1024);    // 16MB (nsplit=2) / 32MB (nsplit=4)

  // choose kv-split granularity by available workspace (part = nsplit*8MB)
  size_t need4 = (size_t)(14 + 32) * 1024 * 1024 + 4096;
  int nsplit = (ws_size >= need4) ? 4 : 2;

  gates_kernel<<<dim3(256), dim3(1024), 0, stream>>>(q, k, v, igw, igb, fgw, fgb, ig, ls);
  scan_kernel<<<dim3(NHEAD), dim3(64), 0, stream>>>(ig, ls, g64, M64, rexpv);
  convert_kernel<<<dim3(256), dim3(256), 0, stream>>>(k, v, KfH, KfL, VfH);
  rebase_kernel<<<dim3(128), dim3(256), 0, stream>>>(g64, M64, gq, Mq);
  attn_kernel<<<dim3(16 * nsplit * 8), dim3(512), 0, stream>>>(q, KfH, KfL, VfH, gq, Mq, part, bpart, nsplit);
  combine_ln_kernel<<<dim3(S_LEN), dim3(256), 0, stream>>>(part, bpart, rexpv, lnw, out, nsplit);
}

// Round 6
// 111.769 us; speedup vs baseline: 1.0730x; 1.0730x over previous
//
#include <hip/hip_runtime.h>
#include <hip/hip_bf16.h>
#include <math.h>

#define S_LEN 2048
#define E_DIM 1024
#define NHEAD 8
#define DHEAD 128
#define MEPS 1e-6f
#define LNEPS 1e-5f

typedef __bf16 bf16x8 __attribute__((ext_vector_type(8)));
typedef float f32x4 __attribute__((ext_vector_type(4)));
typedef float f32x16 __attribute__((ext_vector_type(16)));

__device__ inline void split8(const float* x, bf16x8& hi, bf16x8& lo) {
#pragma unroll
  for (int e = 0; e < 8; ++e) {
    float v = x[e];
    __bf16 h = (__bf16)v;
    hi[e] = h;
    lo[e] = (__bf16)(v - (float)h);
  }
}

__device__ inline int cvtpk(float a, float b) {
  int d;
  asm("v_cvt_pk_bf16_f32 %0, %1, %2" : "=v"(d) : "v"(a), "v"(b));
  return d;
}

// ---------- kernel 1: gates (unchanged, known-good) ----------
__global__ __launch_bounds__(1024) void gates_kernel(
    const float* __restrict__ q, const float* __restrict__ k, const float* __restrict__ v,
    const float* __restrict__ igw, const float* __restrict__ igb,
    const float* __restrict__ fgw, const float* __restrict__ fgb,
    float* __restrict__ ig, double* __restrict__ ls) {
  int t = threadIdx.x, wave = t >> 6, lane = t & 63;
  int c = wave;
  const float* wrow = (c < 8) ? (igw + c * 3072) : (fgw + (c - 8) * 3072);
  float4 wreg[12];
#pragma unroll
  for (int j = 0; j < 12; ++j) wreg[j] = *(const float4*)(wrow + j * 256 + lane * 4);
  int r0 = blockIdx.x * 8;
  for (int r = 0; r < 8; ++r) {
    int row = r0 + r;
    float acc = 0.f;
#pragma unroll
    for (int j = 0; j < 12; ++j) {
      const float* xs = (j < 4) ? (q + (size_t)row * 1024 + j * 256)
                      : (j < 8) ? (k + (size_t)row * 1024 + (j - 4) * 256)
                                : (v + (size_t)row * 1024 + (j - 8) * 256);
      float4 xv = *(const float4*)(xs + lane * 4);
      acc = fmaf(xv.x, wreg[j].x, acc);
      acc = fmaf(xv.y, wreg[j].y, acc);
      acc = fmaf(xv.z, wreg[j].z, acc);
      acc = fmaf(xv.w, wreg[j].w, acc);
    }
#pragma unroll
    for (int off = 1; off < 64; off <<= 1) acc += __shfl_xor(acc, off);
    if (lane == 0) {
      if (c < 8) {
        ig[c * S_LEN + row] = acc + igb[c];
      } else {
        double x = (double)(acc + fgb[c - 8]);
        ls[(c - 8) * S_LEN + row] = fmin(x, 0.0) - log1p(exp(-fabs(x)));
      }
    }
  }
}

// ---------- kernel 2: per-head f64 scan (unchanged) ----------
__global__ void scan_kernel(const float* __restrict__ ig, const double* __restrict__ ls,
                            double* __restrict__ g, double* __restrict__ Mv,
                            float* __restrict__ rexpv) {
  int h = blockIdx.x;
  int lane = threadIdx.x;
  double cs0[32];
  const double* lsp = ls + h * S_LEN + lane * 32;
  double run = 0.0;
#pragma unroll
  for (int e = 0; e < 32; ++e) { run += lsp[e]; cs0[e] = run; }
  double incl = run;
#pragma unroll
  for (int off = 1; off < 64; off <<= 1) {
    double nb = __shfl_up(incl, off);
    if (lane >= off) incl += nb;
  }
  double base = __shfl_up(incl, 1);
  if (lane == 0) base = 0.0;
#pragma unroll
  for (int e = 0; e < 32; ++e) cs0[e] += base;

  const float* igp = ig + h * S_LEN + lane * 32;
  double gv[32];
#pragma unroll
  for (int e = 0; e < 32; ++e) {
    gv[e] = (double)igp[e] - cs0[e];
    g[h * S_LEN + lane * 32 + e] = gv[e];
  }
  double pm = -INFINITY;
#pragma unroll
  for (int e = 0; e < 32; ++e) { pm = fmax(pm, gv[e]); gv[e] = pm; }
  double inclm = pm;
#pragma unroll
  for (int off = 1; off < 64; off <<= 1) {
    double nb = __shfl_up(inclm, off);
    if (lane >= off) inclm = fmax(inclm, nb);
  }
  double basem = __shfl_up(inclm, 1);
  if (lane == 0) basem = -INFINITY;
#pragma unroll
  for (int e = 0; e < 32; ++e) {
    double Mi = fmax(basem, gv[e]);
    Mv[h * S_LEN + lane * 32 + e] = Mi;
    rexpv[h * S_LEN + lane * 32 + e] = __expf(-(float)(cs0[e] + Mi));
  }
}

// ---------- kernel 2c: rebase g/M to f32 per (head, 128-row q-group) ----------
__global__ __launch_bounds__(256) void rebase_kernel(
    const double* __restrict__ g, const double* __restrict__ Mv,
    float* __restrict__ gq, float* __restrict__ Mq) {
  int b = blockIdx.x;         // 128 = 8 heads x 16 groups
  int h = b >> 4, qg = b & 15;
  int tid = threadIdx.x;
  double base = Mv[h * S_LEN + qg * 128];
#pragma unroll
  for (int it = 0; it < 8; ++it) {
    int j = it * 256 + tid;
    gq[(size_t)(h * 16 + qg) * S_LEN + j] = (float)(g[h * S_LEN + j] - base);
  }
  if (tid < 128) {
    int i = qg * 128 + tid;
    Mq[h * S_LEN + i] = (float)(Mv[h * S_LEN + i] - base);
  }
}

// ---------- kernel 3: convert K,V to 32x32-MFMA fragment layouts ----------
// KfH/KfL: [h][kvt32][kch8][lane][8]   elem = K[kvt*32+(l&31)][h*128+kch*16+(l>>5)*8+e]
// VT:      [h][kvt32][f=dt*2+kch][lane][8] elem = V[kvt*32+kch*16+(l>>5)*8+e][h*128+dt*32+(l&31)]
__global__ __launch_bounds__(256) void convert_kernel(
    const float* __restrict__ k, const float* __restrict__ v,
    __bf16* __restrict__ KfH, __bf16* __restrict__ KfL, __bf16* __restrict__ VT) {
  int h = blockIdx.x >> 6, kvt = blockIdx.x & 63;
  int t = threadIdx.x;
  __shared__ float Kl[32][132], Vl[32][132];
  int kvbase = kvt * 32;
#pragma unroll
  for (int it = 0; it < 4; ++it) {
    int fid = it * 256 + t;               // 1024 float4 per tensor
    int r = fid >> 5, c4 = (fid & 31) * 4;
    *(float4*)&Kl[r][c4] = *(const float4*)(k + (size_t)(kvbase + r) * E_DIM + h * DHEAD + c4);
    *(float4*)&Vl[r][c4] = *(const float4*)(v + (size_t)(kvbase + r) * E_DIM + h * DHEAD + c4);
  }
  __syncthreads();
  size_t tb = (size_t)(h * 64 + kvt) * 4096;
#pragma unroll
  for (int it = 0; it < 2; ++it) {
    int slot = it * 256 + t;              // 512 = 8 chunks x 64 lanes
    int f = slot >> 6, l = slot & 63;
    int l31 = l & 31, hi = l >> 5;
    {  // K chunk kch=f
      float buf[8];
#pragma unroll
      for (int e = 0; e < 8; ++e) buf[e] = Kl[l31][f * 16 + hi * 8 + e];
      bf16x8 fh, fl; split8(buf, fh, fl);
      *(bf16x8*)(KfH + tb + (size_t)slot * 8) = fh;
      *(bf16x8*)(KfL + tb + (size_t)slot * 8) = fl;
    }
    {  // V chunk f = dt*2+kch
      int dt = f >> 1, kch = f & 1;
      bf16x8 fh;
#pragma unroll
      for (int e = 0; e < 8; ++e) fh[e] = (__bf16)Vl[kch * 16 + hi * 8 + e][dt * 32 + l31];
      *(bf16x8*)(VT + tb + (size_t)slot * 8) = fh;
    }
  }
}

// ---------- kernel 4: attention, swapped-operand 32x32 MFMA, gload_lds pipeline ----------
__global__ __launch_bounds__(256, 2) void attn_kernel(
    const float* __restrict__ q,
    const __bf16* __restrict__ KfH, const __bf16* __restrict__ KfL,
    const __bf16* __restrict__ VT,
    const float* __restrict__ gq, const float* __restrict__ Mq,
    __bf16* __restrict__ part, float* __restrict__ bpart) {
  int idx = blockIdx.x;
  int qg = 15 - (idx >> 5);          // heavy-first
  int r = idx & 31;
  int h = r & 7;                     // head -> XCD pinned
  int quarter = r >> 3;              // 0..3 kv-quarters
  int Tq = qg + 1;                   // tiles (32 kv rows) per quarter
  int kb_lo = quarter * Tq;
  int tid = threadIdx.x, wave = tid >> 6, lane = tid & 63;
  int l31 = lane & 31, hi = lane >> 5;
  const float scale = 0.08838834764831845f;  // 1/sqrt(128)

  __shared__ char smem[49152];       // 2 bufs x [KH 8K | KL 8K | VT 8K]

  // Q^T B-fragments hi/lo: lane holds q-row (qg*128 + wave*32 + l31), d = kch*16+hi*8+e
  int qrow = qg * 128 + wave * 32 + l31;
  bf16x8 qfh[8], qfl[8];
  {
    const float* qp = q + (size_t)qrow * E_DIM + h * DHEAD + hi * 8;
#pragma unroll
    for (int kch = 0; kch < 8; ++kch) {
      float buf[8];
      *(float4*)&buf[0] = *(const float4*)(qp + kch * 16);
      *(float4*)&buf[4] = *(const float4*)(qp + kch * 16 + 4);
      split8(buf, qfh[kch], qfl[kch]);
    }
  }
  float Mreg = Mq[h * S_LEN + qrow];
  const float* gqh = gq + (size_t)(h * 16 + qg) * S_LEN;

  f32x16 acc[4];
#pragma unroll
  for (int dt = 0; dt < 4; ++dt) acc[dt] = (f32x16)(0.f);
  float bacc = 0.f;

  // stage one 24KB tile (24 x 1KB gload_lds chunks; wave w -> chunks 6w..6w+5)
  size_t laneoff = (size_t)lane * 8;
  auto STAGE = [&](int kb, int buf) {
    size_t tb = (size_t)(h * 64 + kb) * 4096;
    char* lb = smem + buf * 24576;
#pragma unroll
    for (int i = 0; i < 6; ++i) {
      int c = wave * 6 + i;
      const __bf16* src;
      if (c < 8)       src = KfH + tb + (size_t)c * 512 + laneoff;
      else if (c < 16) src = KfL + tb + (size_t)(c - 8) * 512 + laneoff;
      else             src = VT  + tb + (size_t)(c - 16) * 512 + laneoff;
      __builtin_amdgcn_global_load_lds(
          (const __attribute__((address_space(1))) void*)src,
          (__attribute__((address_space(3))) void*)(lb + c * 1024), 16, 0, 0);
    }
  };

  STAGE(kb_lo, 0);
  int cur = 0;
  for (int t = 0; t < Tq; ++t) {
    int kb = kb_lo + t;
    if (t + 1 < Tq) {
      STAGE(kb + 1, cur ^ 1);
      asm volatile("s_waitcnt vmcnt(6)" ::: "memory");
    } else {
      asm volatile("s_waitcnt vmcnt(0)" ::: "memory");
    }
    __builtin_amdgcn_sched_barrier(0);
    asm volatile("s_barrier" ::: "memory");

    // causal tile state (wave-uniform skip)
    int qrelw = qg * 128 + wave * 32 - kb * 32;   // min over lanes
    if (qrelw + 31 >= 0) {
      char* lb = smem + cur * 24576;
      int qrel = qrelw + l31;
      // ---- S^T = K . Q^T  (3-term split) ----
      f32x16 st = (f32x16)(0.f);
      __builtin_amdgcn_s_setprio(1);
#pragma unroll
      for (int kch = 0; kch < 8; ++kch) {
        bf16x8 kh = *(const bf16x8*)(lb + kch * 1024 + lane * 16);
        bf16x8 kl = *(const bf16x8*)(lb + 8192 + kch * 1024 + lane * 16);
        st = __builtin_amdgcn_mfma_f32_32x32x16_bf16(kh, qfh[kch], st, 0, 0, 0);
        st = __builtin_amdgcn_mfma_f32_32x32x16_bf16(kl, qfh[kch], st, 0, 0, 0);
        st = __builtin_amdgcn_mfma_f32_32x32x16_bf16(kh, qfl[kch], st, 0, 0, 0);
      }
      __builtin_amdgcn_s_setprio(0);
      // ---- weights: P^T[kv][q] = S^T * scale * exp(g_kv - M_q), causal ----
      float4 g4[4];
#pragma unroll
      for (int c = 0; c < 4; ++c) g4[c] = *(const float4*)(gqh + kb * 32 + 8 * c + 4 * hi);
      float p[16];
#pragma unroll
      for (int rg = 0; rg < 16; ++rg) {
        int J = (rg & 3) + 8 * (rg >> 2) + 4 * hi;
        float w = st[rg] * scale * __expf(((const float*)&g4[rg >> 2])[rg & 3] - Mreg);
        p[rg] = (J <= qrel) ? w : 0.f;
        bacc += p[rg];
      }
      // ---- pack P^T B-fragments in-register (cvt_pk + permlane32_swap) ----
#pragma unroll
      for (int kch = 0; kch < 2; ++kch) {
        const float* pp = p + kch * 8;
        int a0 = cvtpk(pp[0], pp[1]);
        int a1 = cvtpk(pp[2], pp[3]);
        int a2 = cvtpk(pp[4], pp[5]);
        int a3 = cvtpk(pp[6], pp[7]);
        asm("v_permlane32_swap_b32 %0, %1" : "+v"(a0), "+v"(a2));
        asm("v_permlane32_swap_b32 %0, %1" : "+v"(a1), "+v"(a3));
        union { int w[4]; bf16x8 v; } pb;
        pb.w[0] = a0; pb.w[1] = a1; pb.w[2] = a2; pb.w[3] = a3;
        // ---- O^T += V^T . P^T ----
        __builtin_amdgcn_s_setprio(1);
#pragma unroll
        for (int dt = 0; dt < 4; ++dt) {
          bf16x8 va = *(const bf16x8*)(lb + 16384 + (dt * 2 + kch) * 1024 + lane * 16);
          acc[dt] = __builtin_amdgcn_mfma_f32_32x32x16_bf16(va, pb.v, acc[dt], 0, 0, 0);
        }
        __builtin_amdgcn_s_setprio(0);
      }
    }
    asm volatile("s_barrier" ::: "memory");
    cur ^= 1;
  }

  // ---- epilogue: combine b across lane halves, store bf16 partials ----
  {
    int x = __float_as_int(bacc), y = x;
    asm("v_permlane32_swap_b32 %0, %1" : "+v"(x), "+v"(y));
    float bfull = __int_as_float(x) + __int_as_float(y);
    int task = ((h * 16 + qg) * 4 + quarter);
    if (lane < 32) bpart[task * 128 + wave * 32 + lane] = bfull;
    __bf16* pp = part + (size_t)task * 16384;
#pragma unroll
    for (int dt = 0; dt < 4; ++dt)
#pragma unroll
      for (int rg = 0; rg < 16; ++rg) {
        int row = dt * 32 + (rg & 3) + 8 * (rg >> 2) + 4 * hi;
        pp[row * 128 + wave * 32 + l31] = (__bf16)acc[dt][rg];
      }
  }
}

// ---------- kernel 5: combine partials + normalize + LayerNorm ----------
__global__ __launch_bounds__(256) void combine_ln_kernel(
    const __bf16* __restrict__ part, const float* __restrict__ bpart,
    const float* __restrict__ rexpv, const float* __restrict__ lnw,
    float* __restrict__ out) {
  int t = blockIdx.x;          // token
  int tid = threadIdx.x;
  int qg = t >> 7, qloc = t & 127;
  int e = tid * 4;
  int h = e >> 7, d0 = e & 127;
  int task0 = (h * 16 + qg) * 4;
  float a[4] = {0.f, 0.f, 0.f, 0.f};
  float b = 0.f;
#pragma unroll
  for (int s = 0; s < 4; ++s) {
    const __bf16* pp = part + (size_t)(task0 + s) * 16384;
#pragma unroll
    for (int i = 0; i < 4; ++i) a[i] += (float)pp[(d0 + i) * 128 + qloc];
    b += bpart[(task0 + s) * 128 + qloc];
  }
  float norm = fmaxf(fabsf(b), rexpv[h * S_LEN + t]) + MEPS;
  float inv = 1.f / norm;
  float hv[4];
#pragma unroll
  for (int i = 0; i < 4; ++i) hv[i] = a[i] * inv;

  float sum = hv[0] + hv[1] + hv[2] + hv[3];
  float sq  = hv[0]*hv[0] + hv[1]*hv[1] + hv[2]*hv[2] + hv[3]*hv[3];
#pragma unroll
  for (int off = 1; off < 64; off <<= 1) {
    sum += __shfl_xor(sum, off);
    sq  += __shfl_xor(sq, off);
  }
  __shared__ float ps[4][2];
  int wave = tid >> 6;
  if ((tid & 63) == 0) { ps[wave][0] = sum; ps[wave][1] = sq; }
  __syncthreads();
  float ts = ps[0][0] + ps[1][0] + ps[2][0] + ps[3][0];
  float tq = ps[0][1] + ps[1][1] + ps[2][1] + ps[3][1];
  float mu = ts * (1.f / E_DIM);
  float var = tq * (1.f / E_DIM) - mu * mu;
  float rstd = rsqrtf(var + LNEPS);
  float4 w = *(const float4*)(lnw + e);
  float4 o;
  o.x = (hv[0] - mu) * rstd * w.x;
  o.y = (hv[1] - mu) * rstd * w.y;
  o.z = (hv[2] - mu) * rstd * w.z;
  o.w = (hv[3] - mu) * rstd * w.w;
  *(float4*)(out + (size_t)t * E_DIM + e) = o;
}

extern "C" void kernel_launch(void* const* d_in, const int* in_sizes, int n_in,
                              void* d_out, int out_size, void* d_ws, size_t ws_size,
                              hipStream_t stream) {
  const float* q   = (const float*)d_in[0];
  const float* k   = (const float*)d_in[1];
  const float* v   = (const float*)d_in[2];
  const float* igw = (const float*)d_in[3];
  const float* igb = (const float*)d_in[4];
  const float* fgw = (const float*)d_in[5];
  const float* fgb = (const float*)d_in[6];
  const float* lnw = (const float*)d_in[7];
  float* out = (float*)d_out;

  char* base = (char*)d_ws;
  float*  ig    = (float*)(base + 0);               // 64KB
  float*  rexpv = (float*)(base + 64 * 1024);       // 64KB
  float*  Mq    = (float*)(base + 128 * 1024);      // 64KB
  float*  bpart = (float*)(base + 192 * 1024);      // 256KB
  double* ls    = (double*)(base + 448 * 1024);     // 128KB
  double* g64   = (double*)(base + 576 * 1024);     // 128KB
  double* M64   = (double*)(base + 704 * 1024);     // 128KB
  float*  gq    = (float*)(base + 1024 * 1024);     // 1MB
  __bf16* KfH   = (__bf16*)(base + 2 * 1024 * 1024);    // 4MB
  __bf16* KfL   = (__bf16*)(base + 6 * 1024 * 1024);    // 4MB
  __bf16* VT    = (__bf16*)(base + 10 * 1024 * 1024);   // 4MB
  __bf16* part  = (__bf16*)(base + 14 * 1024 * 1024);   // 16MB

  gates_kernel<<<dim3(256), dim3(1024), 0, stream>>>(q, k, v, igw, igb, fgw, fgb, ig, ls);
  scan_kernel<<<dim3(NHEAD), dim3(64), 0, stream>>>(ig, ls, g64, M64, rexpv);
  convert_kernel<<<dim3(512), dim3(256), 0, stream>>>(k, v, KfH, KfL, VT);
  rebase_kernel<<<dim3(128), dim3(256), 0, stream>>>(g64, M64, gq, Mq);
  attn_kernel<<<dim3(512), dim3(256), 0, stream>>>(q, KfH, KfL, VT, gq, Mq, part, bpart);
  combine_ln_kernel<<<dim3(S_LEN), dim3(256), 0, stream>>>(part, bpart, rexpv, lnw, out);
}